// Round 5
// baseline (224.018 us; speedup 1.0000x reference)
//
#include <hip/hip_runtime.h>
#include <hip/hip_cooperative_groups.h>

namespace cg = cooperative_groups;

// Problem: D=512, H=8, L=4, NE=8, B=32, S=512. fp32 in / fp32 out.
//
// Reduction chain (R3-verified absmax 0.0, R4-verified 3.8e-6):
//   cross-attn Sk=1 -> softmax==1 -> last[b] = (ctx[b]@cWv+cbv)@cWo+cbo,
//   ctx[b] = c0[b]*ctxW[0] + c1[b]*ctxW[1] + ctxb  -> batch factors out:
//   A_i = x_i@cWv (x={ctxW0,ctxW1,ctxb}), A2+=cbv
//   B_i = A_i@cWo, B2+=cbo
//   P_i[s,h] = B_i@spW[h][s], P2+=spb
//   out[b,h,o] = c0[b]*P0 + c1[b]*P1 + P2   (s=sid[b])
// R5: single cooperative kernel, grid.sync() between phases (was 3 dispatches
// with ~2-3us graph gaps each; heads phase now 64 blocks instead of 16).

#define DD 512

__global__ __launch_bounds__(256) void hivemind_fused(
    const float* __restrict__ ctxW,   // (2,512)
    const float* __restrict__ ctxb,   // (512)
    const float* __restrict__ cWv,    // (512,512)
    const float* __restrict__ cbv,    // (512)
    const float* __restrict__ cWo,    // (512,512)
    const float* __restrict__ cbo,    // (512)
    const float* __restrict__ spWp,   // (8,512,64)
    const float* __restrict__ spbp,   // (8,64)
    const float* __restrict__ spWa,   // (8,512,64)
    const float* __restrict__ spba,   // (8,64)
    const float* __restrict__ ctxin,  // (32,2)
    const int*   __restrict__ sid,    // (32)
    float*       __restrict__ wsA,    // (3,512) scratch
    float*       __restrict__ wsB,    // (3,512) scratch
    float*       __restrict__ out)    // pred (32,64) then act (32,64)
{
    __shared__ float sx[3][DD];
    __shared__ float red[16][16][3];
    __shared__ float pv[3][16];

    cg::grid_group grid = cg::this_grid();
    const int t = threadIdx.x;
    const int blk = blockIdx.x;

    // ---------- Phase A: A_i = x_i @ cWv (+cbv for i=2), blocks 0..31 ----------
    if (blk < 32) {
        for (int i = t; i < DD; i += 256) {
            sx[0][i] = ctxW[i];
            sx[1][i] = ctxW[DD + i];
            sx[2][i] = ctxb[i];
        }
        __syncthreads();
        const int c = t & 15, dg = t >> 4;     // 16 cols x 16 d-groups of 32
        const int cbase = blk * 16;
        const float* wp = cWv + (size_t)(dg * 32) * DD + cbase + c;
        float p0 = 0.f, p1 = 0.f, p2 = 0.f;
        #pragma unroll
        for (int j = 0; j < 32; ++j) {
            const float w = wp[(size_t)j * DD];
            const int d = dg * 32 + j;
            p0 += sx[0][d] * w; p1 += sx[1][d] * w; p2 += sx[2][d] * w;
        }
        red[dg][c][0] = p0; red[dg][c][1] = p1; red[dg][c][2] = p2;
        __syncthreads();
        if (t < 48) {
            const int vec = t >> 4, cc = t & 15;
            float s = 0.f;
            #pragma unroll
            for (int g = 0; g < 16; ++g) s += red[g][cc][vec];
            if (vec == 2) s += cbv[cbase + cc];
            wsA[vec * DD + cbase + cc] = s;
        }
    }
    grid.sync();

    // ---------- Phase B: B_i = A_i @ cWo (+cbo for i=2), blocks 0..31 ----------
    if (blk < 32) {
        for (int i = t; i < DD; i += 256) {
            sx[0][i] = wsA[i];
            sx[1][i] = wsA[DD + i];
            sx[2][i] = wsA[2 * DD + i];
        }
        __syncthreads();
        const int c = t & 15, dg = t >> 4;
        const int cbase = blk * 16;
        const float* wp = cWo + (size_t)(dg * 32) * DD + cbase + c;
        float p0 = 0.f, p1 = 0.f, p2 = 0.f;
        #pragma unroll
        for (int j = 0; j < 32; ++j) {
            const float w = wp[(size_t)j * DD];
            const int d = dg * 32 + j;
            p0 += sx[0][d] * w; p1 += sx[1][d] * w; p2 += sx[2][d] * w;
        }
        red[dg][c][0] = p0; red[dg][c][1] = p1; red[dg][c][2] = p2;
        __syncthreads();
        if (t < 48) {
            const int vec = t >> 4, cc = t & 15;
            float s = 0.f;
            #pragma unroll
            for (int g = 0; g < 16; ++g) s += red[g][cc][vec];
            if (vec == 2) s += cbo[cbase + cc];
            wsB[vec * DD + cbase + cc] = s;
        }
    }
    grid.sync();

    // ---------- Phase H: heads + batch broadcast, all 64 blocks ----------
    {
        const int s = blk & 7, h = (blk >> 3) & 1, q = blk >> 4;  // o-quarter
        for (int i = t; i < DD; i += 256) {
            sx[0][i] = wsB[i];
            sx[1][i] = wsB[DD + i];
            sx[2][i] = wsB[2 * DD + i];
        }
        __syncthreads();
        const float* W    = (h ? spWa : spWp) + (size_t)s * DD * 64;
        const float* bias = (h ? spba : spbp) + s * 64;
        const int ol = t & 15, dg = t >> 4;    // 16 outs x 16 d-groups of 32
        const int o = q * 16 + ol;
        const float* wp = W + (size_t)(dg * 32) * 64 + o;
        float p0 = 0.f, p1 = 0.f, p2 = 0.f;
        #pragma unroll
        for (int j = 0; j < 32; ++j) {
            const float w = wp[(size_t)j * 64];
            const int d = dg * 32 + j;
            p0 += sx[0][d] * w; p1 += sx[1][d] * w; p2 += sx[2][d] * w;
        }
        red[dg][ol][0] = p0; red[dg][ol][1] = p1; red[dg][ol][2] = p2;
        __syncthreads();
        if (t < 48) {
            const int vec = t >> 4, oo = t & 15;
            float a = 0.f;
            #pragma unroll
            for (int g = 0; g < 16; ++g) a += red[g][oo][vec];
            if (vec == 2) a += bias[q * 16 + oo];
            pv[vec][oo] = a;
        }
        __syncthreads();
        if (t < 16) {
            const float v0 = pv[0][t], v1 = pv[1][t], v2 = pv[2][t];
            for (int b = 0; b < 32; ++b) {
                if (sid[b] == s) {
                    out[h * 2048 + b * 64 + q * 16 + t] =
                        ctxin[2 * b] * v0 + ctxin[2 * b + 1] * v1 + v2;
                }
            }
        }
    }
}

extern "C" void kernel_launch(void* const* d_in, const int* in_sizes, int n_in,
                              void* d_out, int out_size, void* d_ws, size_t ws_size,
                              hipStream_t stream) {
    // 0 x_batch, 1 context_batch, 2 specialist_ids, 3 emb, 4-11 attn, 12-15 ln,
    // 16-19 ffn, 20 ctxW, 21 ctxb, 22-25 cWq/cWk, 26 cWv, 27 cbv, 28 cWo,
    // 29 cbo, 30 spWp, 31 spbp, 32 spWa, 33 spba
    const float* ctxin = (const float*)d_in[1];
    const int*   sid   = (const int*)d_in[2];
    const float* ctxW  = (const float*)d_in[20];
    const float* ctxb  = (const float*)d_in[21];
    const float* cWv   = (const float*)d_in[26];
    const float* cbv   = (const float*)d_in[27];
    const float* cWo   = (const float*)d_in[28];
    const float* cbo   = (const float*)d_in[29];
    const float* spWp  = (const float*)d_in[30];
    const float* spbp  = (const float*)d_in[31];
    const float* spWa  = (const float*)d_in[32];
    const float* spba  = (const float*)d_in[33];
    float* out = (float*)d_out;
    float* wsA = (float*)d_ws;
    float* wsB = wsA + 3 * DD;

    void* args[] = {
        (void*)&ctxW, (void*)&ctxb, (void*)&cWv, (void*)&cbv,
        (void*)&cWo,  (void*)&cbo,  (void*)&spWp, (void*)&spbp,
        (void*)&spWa, (void*)&spba, (void*)&ctxin, (void*)&sid,
        (void*)&wsA,  (void*)&wsB,  (void*)&out
    };
    hipLaunchCooperativeKernel((const void*)hivemind_fused,
                               dim3(64), dim3(256), args, 0, stream);
}

// Round 6
// 158.546 us; speedup vs baseline: 1.4130x; 1.4130x over previous
//
#include <hip/hip_runtime.h>

// Problem: D=512, H=8, L=4, NE=8, B=32, S=512. fp32 in / fp32 out.
//
// Reduction chain (R3-verified absmax 0.0, R4 3.8e-6, R5 6.1e-5):
//   cross-attn Sk=1 -> softmax==1 -> last[b] = (ctx[b]@cWv+cbv)@cWo+cbo,
//   ctx[b] = c0[b]*ctxW[0] + c1[b]*ctxW[1] + ctxb  -> batch factors out:
//     A_i = x_i@cWv (x={ctxW0,ctxW1,ctxb}), A2+=cbv
//     B_i = A_i@cWo, B2+=cbo
//     P_i[s,h] = B_i@spW[h][s], P2+=spb
//     out[b,h,o] = c0[b]*P0 + c1[b]*P1 + P2   (s=sid[b])
//
// R6: ONE regular dispatch (R5 showed graph-captured cooperative launch costs
// ~70us). Inter-phase sync via per-block magic flags in ws: ws is re-poisoned
// to 0xAA before every launch, so flags start != MAGIC with no init dispatch.
// Cross-XCD visibility: vector data + flags via agent-scope atomics (G16).
// All weight slices preloaded into registers at t=0 so HBM latency overlaps
// the barrier waits. 64 blocks << 256 CUs -> co-resident, spin is safe.

#define DD 512
#define MAGIC 0x13579BDF

__global__ __launch_bounds__(256) void hivemind_one(
    const float* __restrict__ ctxW,   // (2,512)
    const float* __restrict__ ctxb,   // (512)
    const float* __restrict__ cWv,    // (512,512)
    const float* __restrict__ cbv,    // (512)
    const float* __restrict__ cWo,    // (512,512)
    const float* __restrict__ cbo,    // (512)
    const float* __restrict__ spWp,   // (8,512,64)
    const float* __restrict__ spbp,   // (8,64)
    const float* __restrict__ spWa,   // (8,512,64)
    const float* __restrict__ spba,   // (8,64)
    const float* __restrict__ ctxin,  // (32,2)
    const int*   __restrict__ sid,    // (32)
    float*       __restrict__ wsA,    // (3,512) scratch
    float*       __restrict__ wsB,    // (3,512) scratch
    int*         __restrict__ flagA,  // (32) poison-initialized
    int*         __restrict__ flagB,  // (32) poison-initialized
    float*       __restrict__ out)    // pred (32,64) then act (32,64)
{
    __shared__ float sx[3][DD];
    __shared__ float red[16][16][3];
    __shared__ float pvv[3][16];

    const int t   = threadIdx.x;
    const int blk = blockIdx.x;
    const int c   = t & 15, dg = t >> 4;        // 16 cols x 16 d-groups of 32
    const int s   = blk & 7, h = (blk >> 3) & 1, q = blk >> 4;

    // ---------- stage ctx vectors (blocks 0..31) : issued first ----------
    float a0 = 0.f, a1 = 0.f, b0 = 0.f, b1 = 0.f, e0 = 0.f, e1 = 0.f;
    if (blk < 32) {
        a0 = ctxW[t];        a1 = ctxW[t + 256];
        b0 = ctxW[DD + t];   b1 = ctxW[DD + t + 256];
        e0 = ctxb[t];        e1 = ctxb[t + 256];
    }

    // ---------- register preloads (latency hidden behind phases/waits) ----
    float wv[32], wo[32];
    if (blk < 32) {
        const int cbase = blk * 16;
        const float* pv_ = cWv + (size_t)(dg * 32) * DD + cbase + c;
        const float* po_ = cWo + (size_t)(dg * 32) * DD + cbase + c;
        #pragma unroll
        for (int j = 0; j < 32; ++j) wv[j] = pv_[(size_t)j * DD];
        #pragma unroll
        for (int j = 0; j < 32; ++j) wo[j] = po_[(size_t)j * DD];
    }
    float wh[32];
    {
        const float* W   = (h ? spWa : spWp) + (size_t)s * DD * 64;
        const float* ph_ = W + (size_t)(dg * 32) * 64 + q * 16 + c;
        #pragma unroll
        for (int j = 0; j < 32; ++j) wh[j] = ph_[(size_t)j * 64];
    }

    if (blk < 32) {
        const int cbase = blk * 16;

        // -------- Phase A: A_i = x_i @ cWv (+cbv) --------
        sx[0][t] = a0; sx[0][t + 256] = a1;
        sx[1][t] = b0; sx[1][t + 256] = b1;
        sx[2][t] = e0; sx[2][t + 256] = e1;
        __syncthreads();
        {
            float p0 = 0.f, p1 = 0.f, p2 = 0.f;
            #pragma unroll
            for (int j = 0; j < 32; ++j) {
                const int d = dg * 32 + j;
                const float w = wv[j];
                p0 += sx[0][d] * w; p1 += sx[1][d] * w; p2 += sx[2][d] * w;
            }
            red[dg][c][0] = p0; red[dg][c][1] = p1; red[dg][c][2] = p2;
        }
        __syncthreads();
        if (t < 48) {
            const int vec = t >> 4, cc = t & 15;
            float acc = 0.f;
            #pragma unroll
            for (int g = 0; g < 16; ++g) acc += red[g][cc][vec];
            if (vec == 2) acc += cbv[cbase + cc];
            __hip_atomic_store(&wsA[vec * DD + cbase + cc], acc,
                               __ATOMIC_RELAXED, __HIP_MEMORY_SCOPE_AGENT);
        }
        __syncthreads();   // waves drain their stores before flag
        if (t == 0)
            __hip_atomic_store(&flagA[blk], MAGIC,
                               __ATOMIC_RELEASE, __HIP_MEMORY_SCOPE_AGENT);

        // -------- wait all A, then Phase B: B_i = A_i @ cWo (+cbo) --------
        if (t < 32)
            while (__hip_atomic_load(&flagA[t], __ATOMIC_ACQUIRE,
                                     __HIP_MEMORY_SCOPE_AGENT) != MAGIC) {}
        __syncthreads();
        for (int i = t; i < 3 * DD; i += 256)
            (&sx[0][0])[i] = __hip_atomic_load(&wsA[i], __ATOMIC_RELAXED,
                                               __HIP_MEMORY_SCOPE_AGENT);
        __syncthreads();
        {
            float p0 = 0.f, p1 = 0.f, p2 = 0.f;
            #pragma unroll
            for (int j = 0; j < 32; ++j) {
                const int d = dg * 32 + j;
                const float w = wo[j];
                p0 += sx[0][d] * w; p1 += sx[1][d] * w; p2 += sx[2][d] * w;
            }
            red[dg][c][0] = p0; red[dg][c][1] = p1; red[dg][c][2] = p2;
        }
        __syncthreads();
        if (t < 48) {
            const int vec = t >> 4, cc = t & 15;
            float acc = 0.f;
            #pragma unroll
            for (int g = 0; g < 16; ++g) acc += red[g][cc][vec];
            if (vec == 2) acc += cbo[cbase + cc];
            __hip_atomic_store(&wsB[vec * DD + cbase + cc], acc,
                               __ATOMIC_RELAXED, __HIP_MEMORY_SCOPE_AGENT);
        }
        __syncthreads();
        if (t == 0)
            __hip_atomic_store(&flagB[blk], MAGIC,
                               __ATOMIC_RELEASE, __HIP_MEMORY_SCOPE_AGENT);
    }

    // -------- wait all B (all 64 blocks), then Phase H --------
    if (t < 32)
        while (__hip_atomic_load(&flagB[t], __ATOMIC_ACQUIRE,
                                 __HIP_MEMORY_SCOPE_AGENT) != MAGIC) {}
    __syncthreads();
    for (int i = t; i < 3 * DD; i += 256)
        (&sx[0][0])[i] = __hip_atomic_load(&wsB[i], __ATOMIC_RELAXED,
                                           __HIP_MEMORY_SCOPE_AGENT);
    __syncthreads();
    {
        float p0 = 0.f, p1 = 0.f, p2 = 0.f;
        #pragma unroll
        for (int j = 0; j < 32; ++j) {
            const int d = dg * 32 + j;
            const float w = wh[j];
            p0 += sx[0][d] * w; p1 += sx[1][d] * w; p2 += sx[2][d] * w;
        }
        red[dg][c][0] = p0; red[dg][c][1] = p1; red[dg][c][2] = p2;
    }
    __syncthreads();
    if (t < 48) {
        const int vec = t >> 4, oo = t & 15;
        float acc = 0.f;
        #pragma unroll
        for (int g = 0; g < 16; ++g) acc += red[g][oo][vec];
        if (vec == 2) acc += (h ? spba : spbp)[s * 64 + q * 16 + oo];
        pvv[vec][oo] = acc;
    }
    __syncthreads();
    if (t < 16) {
        const float v0 = pvv[0][t], v1 = pvv[1][t], v2 = pvv[2][t];
        for (int b = 0; b < 32; ++b) {
            if (sid[b] == s) {
                out[h * 2048 + b * 64 + q * 16 + t] =
                    ctxin[2 * b] * v0 + ctxin[2 * b + 1] * v1 + v2;
            }
        }
    }
}

extern "C" void kernel_launch(void* const* d_in, const int* in_sizes, int n_in,
                              void* d_out, int out_size, void* d_ws, size_t ws_size,
                              hipStream_t stream) {
    // 0 x_batch, 1 context_batch, 2 specialist_ids, 3 emb, 4-11 attn, 12-15 ln,
    // 16-19 ffn, 20 ctxW, 21 ctxb, 22-25 cWq/cWk, 26 cWv, 27 cbv, 28 cWo,
    // 29 cbo, 30 spWp, 31 spbp, 32 spWa, 33 spba
    const float* ctxin = (const float*)d_in[1];
    const int*   sid   = (const int*)d_in[2];
    const float* ctxW  = (const float*)d_in[20];
    const float* ctxb  = (const float*)d_in[21];
    const float* cWv   = (const float*)d_in[26];
    const float* cbv   = (const float*)d_in[27];
    const float* cWo   = (const float*)d_in[28];
    const float* cbo   = (const float*)d_in[29];
    const float* spWp  = (const float*)d_in[30];
    const float* spbp  = (const float*)d_in[31];
    const float* spWa  = (const float*)d_in[32];
    const float* spba  = (const float*)d_in[33];
    float* out  = (float*)d_out;
    float* wsA  = (float*)d_ws;              // floats [0,1536)
    float* wsB  = wsA + 3 * DD;              // floats [1536,3072)
    int* flagA  = (int*)d_ws + 4096;         // poison 0xAAAAAAAA != MAGIC
    int* flagB  = flagA + 32;

    hivemind_one<<<dim3(64), dim3(256), 0, stream>>>(
        ctxW, ctxb, cWv, cbv, cWo, cbo,
        spWp, spbp, spWa, spba, ctxin, sid,
        wsA, wsB, flagA, flagB, out);
}